// Round 2
// baseline (966.038 us; speedup 1.0000x reference)
//
#include <hip/hip_runtime.h>
#include <stdint.h>

typedef float f32x4 __attribute__((ext_vector_type(4)));
typedef short s16x8 __attribute__((ext_vector_type(8)));
typedef short s16x4 __attribute__((ext_vector_type(4)));

#define MFMA16(a, b, c) __builtin_amdgcn_mfma_f32_16x16x32_bf16(a, b, c, 0, 0, 0)

__device__ __forceinline__ unsigned short f2bf(float f) {
  union { float f; uint32_t u; } v; v.f = f;
  return (unsigned short)((v.u + 0x7FFFu + ((v.u >> 16) & 1u)) >> 16);
}
__device__ __forceinline__ float bf2f(unsigned short s) {
  union { float f; uint32_t u; } v; v.u = ((uint32_t)s) << 16;
  return v.f;
}
__device__ __forceinline__ s16x8 cvt8(const float* p) {
  f32x4 a = *(const f32x4*)p;
  f32x4 b = *(const f32x4*)(p + 4);
  s16x8 t;
  t[0] = (short)f2bf(a[0]); t[1] = (short)f2bf(a[1]);
  t[2] = (short)f2bf(a[2]); t[3] = (short)f2bf(a[3]);
  t[4] = (short)f2bf(b[0]); t[5] = (short)f2bf(b[1]);
  t[6] = (short)f2bf(b[2]); t[7] = (short)f2bf(b[3]);
  return t;
}

// ---------------------------------------------------------------------------
// Stage 1: Y = X @ W^T + b. W staged in LDS as bf16 (XOR-swizzled) to keep
// VGPR count low (occupancy). Output layouts identical to the verified R0.
// ---------------------------------------------------------------------------
__global__ __launch_bounds__(256) void proj_kernel(
    const float* __restrict__ Xq, const float* __restrict__ Xk, const float* __restrict__ Xv,
    const float* __restrict__ Wq, const float* __restrict__ bq,
    const float* __restrict__ Wk, const float* __restrict__ bk,
    const float* __restrict__ Wv, const float* __restrict__ bv,
    unsigned short* __restrict__ Qt, unsigned short* __restrict__ Kt,
    unsigned short* __restrict__ Vf) {
  __shared__ unsigned char Wsh[32768];  // [128][128] bf16, row stride 256B, byte ^= (row&7)<<4

  const int ty = blockIdx.y;
  const float* X = (ty == 0) ? Xq : (ty == 1) ? Xk : Xv;
  const float* W = (ty == 0) ? Wq : (ty == 1) ? Wk : Wv;
  const float* B = (ty == 0) ? bq : (ty == 1) ? bk : bv;
  unsigned short* out = (ty == 0) ? Qt : (ty == 1) ? Kt : Vf;
  const bool transposed = (ty != 2);

  const int tid = threadIdx.x;
  const int lane = tid & 63;
  const int wave = tid >> 6;
  const int l15 = lane & 15;
  const int g = lane >> 4;  // 0..3

  // cooperative W -> LDS (bf16, swizzled)
  {
    const int r = tid >> 1;
    const int cb = (tid & 1) * 64;
    const float* wp = W + (size_t)r * 128 + cb;
#pragma unroll
    for (int c8 = 0; c8 < 8; ++c8) {
      s16x8 w = cvt8(wp + 8 * c8);
      const int byte = r * 256 + ((cb * 2 + c8 * 16) ^ ((r & 7) << 4));
      *(s16x8*)(Wsh + byte) = w;
    }
  }
  __syncthreads();

  auto wfrag = [&](int f, int kc) -> s16x8 {
    const int row = 16 * f + l15;
    return *(const s16x8*)(Wsh + row * 256 + ((64 * kc + 16 * g) ^ ((row & 7) << 4)));
  };

  if (transposed) {
    float bias_s[8];
#pragma unroll
    for (int f = 0; f < 8; ++f) bias_s[f] = B[16 * f + l15];

    for (int t = 0; t < 8; ++t) {
      const int jb = blockIdx.x * 512 + t * 64 + wave * 16;
      const int jrow = jb + (l15 >> 2) + 4 * (l15 & 3);
      const float* xr = X + (size_t)jrow * 128 + 8 * g;
      s16x8 xf[4];
#pragma unroll
      for (int kc = 0; kc < 4; ++kc) xf[kc] = cvt8(xr + 32 * kc);

      f32x4 acc[8];
#pragma unroll
      for (int f = 0; f < 8; ++f) acc[f] = (f32x4){0.f, 0.f, 0.f, 0.f};
#pragma unroll
      for (int kc = 0; kc < 4; ++kc)
#pragma unroll
        for (int f = 0; f < 8; ++f) acc[f] = MFMA16(xf[kc], wfrag(f, kc), acc[f]);

      const int n = jb >> 9;
      const int c0 = (jb & 511) >> 2;
#pragma unroll
      for (int f = 0; f < 8; ++f) {
        const int h = 128 * g + 16 * f + l15;
        s16x4 pv;
#pragma unroll
        for (int r = 0; r < 4; ++r) pv[r] = (short)f2bf(acc[f][r] + bias_s[f]);
        *(s16x4*)(out + (size_t)n * 65536 + (size_t)h * 128 + c0) = pv;
      }
    }
  } else {
    f32x4 bias_v[8];
#pragma unroll
    for (int f = 0; f < 8; ++f) bias_v[f] = *(const f32x4*)(B + 16 * f + 4 * g);

    for (int t = 0; t < 8; ++t) {
      const int jb = blockIdx.x * 512 + t * 64 + wave * 16;
      const int jrow = jb + l15;
      const float* xr = X + (size_t)jrow * 128 + 8 * g;
      s16x8 xf[4];
#pragma unroll
      for (int kc = 0; kc < 4; ++kc) xf[kc] = cvt8(xr + 32 * kc);

      f32x4 acc[8];
#pragma unroll
      for (int f = 0; f < 8; ++f) acc[f] = (f32x4){0.f, 0.f, 0.f, 0.f};
#pragma unroll
      for (int kc = 0; kc < 4; ++kc)
#pragma unroll
        for (int f = 0; f < 8; ++f) acc[f] = MFMA16(wfrag(f, kc), xf[kc], acc[f]);

      const int j = jb + l15;
#pragma unroll
      for (int f = 0; f < 8; ++f) {
        const int cc0 = 16 * f + 4 * g;
        s16x4 pv;
#pragma unroll
        for (int r = 0; r < 4; ++r) pv[r] = (short)f2bf(acc[f][r] + bias_v[f][r]);
        *(s16x4*)(out + (size_t)j * 128 + cc0) = pv;
      }
    }
  }
}

// ---------------------------------------------------------------------------
// Stage 2, two-pass flash-style per (head, 64-row Q tile):
//   pass 1: S = QK^T, rowsum(exp) only (registers, no LDS)
//   pass 2: per 64-col chunk: recompute S, write normalized attn (fp32, NT),
//           stage bf16 P-chunk in 16KB double-buffered LDS, PV-accumulate.
// ---------------------------------------------------------------------------
__global__ __launch_bounds__(256) void attn_kernel(
    const unsigned short* __restrict__ Qt, const unsigned short* __restrict__ Kt,
    const unsigned short* __restrict__ Vf, float* __restrict__ out0,
    float* __restrict__ attn_out) {
  __shared__ unsigned char Psh[16384];  // 2 x [64 rows][128B] bf16, byte ^= (row&7)<<4

  const int tid = threadIdx.x;
  const int lane = tid & 63;
  const int wave = tid >> 6;
  const int l15 = lane & 15;
  const int g = lane >> 4;

  // XCD-aware bijective swizzle (4096 % 8 == 0)
  const int bid = blockIdx.x;
  const int nb = (bid & 7) * 512 + (bid >> 3);
  const int head = nb >> 3;
  const int h0 = (nb & 7) * 64;

  const unsigned short* qbase =
      Qt + (size_t)head * 65536 + (size_t)(h0 + 16 * wave + l15) * 128 + 8 * g;
  s16x8 qf[4];
#pragma unroll
  for (int kc = 0; kc < 4; ++kc) qf[kc] = *(const s16x8*)(qbase + 32 * kc);

  const unsigned short* kbase = Kt + (size_t)head * 65536 + (size_t)l15 * 128 + 8 * g;
  const float scale = 0.08838834764831845f;  // 1/sqrt(128)

  auto loadK = [&](s16x8* kf, int k16) {
    const unsigned short* kp = kbase + k16 * 2048;
#pragma unroll
    for (int kc = 0; kc < 4; ++kc) kf[kc] = *(const s16x8*)(kp + 32 * kc);
  };

  // ---- pass 1: rowsum only ----
  float rsum[4] = {0.f, 0.f, 0.f, 0.f};
  {
    s16x8 ka[4], kb[4];
    loadK(ka, 0);
    for (int k16 = 0; k16 < 32; k16 += 2) {
      loadK(kb, k16 + 1);
      {
        f32x4 a = {0.f, 0.f, 0.f, 0.f};
#pragma unroll
        for (int kc = 0; kc < 4; ++kc) a = MFMA16(qf[kc], ka[kc], a);
#pragma unroll
        for (int r = 0; r < 4; ++r) rsum[r] += __expf(a[r] * scale);
      }
      if (k16 + 2 < 32) loadK(ka, k16 + 2);
      {
        f32x4 a = {0.f, 0.f, 0.f, 0.f};
#pragma unroll
        for (int kc = 0; kc < 4; ++kc) a = MFMA16(qf[kc], kb[kc], a);
#pragma unroll
        for (int r = 0; r < 4; ++r) rsum[r] += __expf(a[r] * scale);
      }
    }
  }
  float inv[4];
#pragma unroll
  for (int r = 0; r < 4; ++r) {
    float s = rsum[r];
    s += __shfl_xor(s, 1); s += __shfl_xor(s, 2);
    s += __shfl_xor(s, 4); s += __shfl_xor(s, 8);
    inv[r] = 1.0f / s;
  }

  // ---- pass 2: attn write + PV ----
  f32x4 acc2[8];
#pragma unroll
  for (int f = 0; f < 8; ++f) acc2[f] = (f32x4){0.f, 0.f, 0.f, 0.f};

  const unsigned short* vbase = Vf + (size_t)head * 65536 + (size_t)l15 * 512 + 8 * g;
  float* ap = attn_out + (size_t)head * 262144 + (size_t)(h0 + 16 * wave) * 512;
  const int prow = 16 * wave + l15;
  const int psw = (prow & 7) << 4;

  for (int ch = 0; ch < 8; ++ch) {
    const int bb = (ch & 1) * 8192;
    // early V issue (kc=0); arrival forced at the barrier, hidden under S-compute
    s16x8 vf[8];
#pragma unroll
    for (int f = 0; f < 8; ++f)
      vf[f] = *(const s16x8*)(vbase + (ch * 2) * 32 + (size_t)f * 8192);

    // S recompute for 4 sub-chunks of 16 cols
#pragma unroll
    for (int s = 0; s < 4; ++s) {
      const int k16 = ch * 4 + s;
      s16x8 kf[4];
      loadK(kf, k16);
      f32x4 a = {0.f, 0.f, 0.f, 0.f};
#pragma unroll
      for (int kc = 0; kc < 4; ++kc) a = MFMA16(qf[kc], kf[kc], a);
#pragma unroll
      for (int r = 0; r < 4; ++r) {
        const float e = __expf(a[r] * scale);
        const int row = 16 * wave + 4 * g + r;
        *(unsigned short*)(Psh + bb + row * 128 + ((s * 32 + l15 * 2) ^ ((row & 7) << 4))) =
            f2bf(e);
        __builtin_nontemporal_store(
            e * inv[r], ap + (size_t)(4 * g + r) * 512 + ch * 64 + s * 16 + l15);
      }
    }
    __syncthreads();

    // PV kc=0
    {
      s16x8 pa = *(const s16x8*)(Psh + bb + prow * 128 + ((16 * g) ^ psw));
#pragma unroll
      for (int f = 0; f < 8; ++f) acc2[f] = MFMA16(pa, vf[f], acc2[f]);
    }
    // reload V (kc=1) and PV kc=1
#pragma unroll
    for (int f = 0; f < 8; ++f)
      vf[f] = *(const s16x8*)(vbase + (ch * 2 + 1) * 32 + (size_t)f * 8192);
    {
      s16x8 pa = *(const s16x8*)(Psh + bb + prow * 128 + ((64 + 16 * g) ^ psw));
#pragma unroll
      for (int f = 0; f < 8; ++f) acc2[f] = MFMA16(pa, vf[f], acc2[f]);
    }
  }

  // ctxt store (normalized, NT)
  float* op = out0 + (size_t)head * 65536 + (size_t)(h0 + 16 * wave + 4 * g) * 128 + l15;
#pragma unroll
  for (int f = 0; f < 8; ++f)
#pragma unroll
    for (int r = 0; r < 4; ++r)
      __builtin_nontemporal_store(acc2[f][r] * inv[r], op + (size_t)r * 128 + f * 16);
}

extern "C" void kernel_launch(void* const* d_in, const int* in_sizes, int n_in,
                              void* d_out, int out_size, void* d_ws, size_t ws_size,
                              hipStream_t stream) {
  const float* q  = (const float*)d_in[0];
  const float* k  = (const float*)d_in[1];
  const float* v  = (const float*)d_in[2];
  const float* Wq = (const float*)d_in[3];
  const float* bq = (const float*)d_in[4];
  const float* Wk = (const float*)d_in[5];
  const float* bk = (const float*)d_in[6];
  const float* Wv = (const float*)d_in[7];
  const float* bv = (const float*)d_in[8];

  unsigned short* Qt = (unsigned short*)d_ws;       // 64 MiB
  unsigned short* Kt = Qt + 33554432;               // 64 MiB
  unsigned short* Vf = Kt + 33554432;               // 64 MiB
  float* out0 = (float*)d_out;                      // 33,554,432 fp32
  float* attn = out0 + 33554432;                    // 134,217,728 fp32

  dim3 pgrid(512, 3, 1);
  proj_kernel<<<pgrid, 256, 0, stream>>>(q, k, v, Wq, bq, Wk, bk, Wv, bv, Qt, Kt, Vf);
  attn_kernel<<<4096, 256, 0, stream>>>(Qt, Kt, Vf, out0, attn);
}

// Round 3
// 848.793 us; speedup vs baseline: 1.1381x; 1.1381x over previous
//
#include <hip/hip_runtime.h>
#include <stdint.h>

typedef float f32x4 __attribute__((ext_vector_type(4)));
typedef short s16x8 __attribute__((ext_vector_type(8)));
typedef short s16x4 __attribute__((ext_vector_type(4)));

#define MFMA16(a, b, c) __builtin_amdgcn_mfma_f32_16x16x32_bf16(a, b, c, 0, 0, 0)

__device__ __forceinline__ unsigned short f2bf(float f) {
  union { float f; uint32_t u; } v; v.f = f;
  return (unsigned short)((v.u + 0x7FFFu + ((v.u >> 16) & 1u)) >> 16);
}
__device__ __forceinline__ float bf2f(unsigned short s) {
  union { float f; uint32_t u; } v; v.u = ((uint32_t)s) << 16;
  return v.f;
}
__device__ __forceinline__ s16x8 cvt8(const float* p) {
  f32x4 a = *(const f32x4*)p;
  f32x4 b = *(const f32x4*)(p + 4);
  s16x8 t;
  t[0] = (short)f2bf(a[0]); t[1] = (short)f2bf(a[1]);
  t[2] = (short)f2bf(a[2]); t[3] = (short)f2bf(a[3]);
  t[4] = (short)f2bf(b[0]); t[5] = (short)f2bf(b[1]);
  t[6] = (short)f2bf(b[2]); t[7] = (short)f2bf(b[3]);
  return t;
}

// ---------------------------------------------------------------------------
// Stage 1: Y = X @ W^T + b. W staged in LDS (bf16, XOR-swizzled). Same as R1.
// ---------------------------------------------------------------------------
__global__ __launch_bounds__(256) void proj_kernel(
    const float* __restrict__ Xq, const float* __restrict__ Xk, const float* __restrict__ Xv,
    const float* __restrict__ Wq, const float* __restrict__ bq,
    const float* __restrict__ Wk, const float* __restrict__ bk,
    const float* __restrict__ Wv, const float* __restrict__ bv,
    unsigned short* __restrict__ Qt, unsigned short* __restrict__ Kt,
    unsigned short* __restrict__ Vf) {
  __shared__ unsigned char Wsh[32768];  // [128][128] bf16, stride 256B, byte ^= (row&7)<<4

  const int ty = blockIdx.y;
  const float* X = (ty == 0) ? Xq : (ty == 1) ? Xk : Xv;
  const float* W = (ty == 0) ? Wq : (ty == 1) ? Wk : Wv;
  const float* B = (ty == 0) ? bq : (ty == 1) ? bk : bv;
  unsigned short* out = (ty == 0) ? Qt : (ty == 1) ? Kt : Vf;
  const bool transposed = (ty != 2);

  const int tid = threadIdx.x;
  const int lane = tid & 63;
  const int wave = tid >> 6;
  const int l15 = lane & 15;
  const int g = lane >> 4;

  {
    const int r = tid >> 1;
    const int cb = (tid & 1) * 64;
    const float* wp = W + (size_t)r * 128 + cb;
#pragma unroll
    for (int c8 = 0; c8 < 8; ++c8) {
      s16x8 w = cvt8(wp + 8 * c8);
      const int byte = r * 256 + ((cb * 2 + c8 * 16) ^ ((r & 7) << 4));
      *(s16x8*)(Wsh + byte) = w;
    }
  }
  __syncthreads();

  auto wfrag = [&](int f, int kc) -> s16x8 {
    const int row = 16 * f + l15;
    return *(const s16x8*)(Wsh + row * 256 + ((64 * kc + 16 * g) ^ ((row & 7) << 4)));
  };

  if (transposed) {
    float bias_s[8];
#pragma unroll
    for (int f = 0; f < 8; ++f) bias_s[f] = B[16 * f + l15];

    for (int t = 0; t < 8; ++t) {
      const int jb = blockIdx.x * 512 + t * 64 + wave * 16;
      const int jrow = jb + (l15 >> 2) + 4 * (l15 & 3);
      const float* xr = X + (size_t)jrow * 128 + 8 * g;
      s16x8 xf[4];
#pragma unroll
      for (int kc = 0; kc < 4; ++kc) xf[kc] = cvt8(xr + 32 * kc);

      f32x4 acc[8];
#pragma unroll
      for (int f = 0; f < 8; ++f) acc[f] = (f32x4){0.f, 0.f, 0.f, 0.f};
#pragma unroll
      for (int kc = 0; kc < 4; ++kc)
#pragma unroll
        for (int f = 0; f < 8; ++f) acc[f] = MFMA16(xf[kc], wfrag(f, kc), acc[f]);

      const int n = jb >> 9;
      const int c0 = (jb & 511) >> 2;
#pragma unroll
      for (int f = 0; f < 8; ++f) {
        const int h = 128 * g + 16 * f + l15;
        s16x4 pv;
#pragma unroll
        for (int r = 0; r < 4; ++r) pv[r] = (short)f2bf(acc[f][r] + bias_s[f]);
        *(s16x4*)(out + (size_t)n * 65536 + (size_t)h * 128 + c0) = pv;
      }
    }
  } else {
    f32x4 bias_v[8];
#pragma unroll
    for (int f = 0; f < 8; ++f) bias_v[f] = *(const f32x4*)(B + 16 * f + 4 * g);

    for (int t = 0; t < 8; ++t) {
      const int jb = blockIdx.x * 512 + t * 64 + wave * 16;
      const int jrow = jb + l15;
      const float* xr = X + (size_t)jrow * 128 + 8 * g;
      s16x8 xf[4];
#pragma unroll
      for (int kc = 0; kc < 4; ++kc) xf[kc] = cvt8(xr + 32 * kc);

      f32x4 acc[8];
#pragma unroll
      for (int f = 0; f < 8; ++f) acc[f] = (f32x4){0.f, 0.f, 0.f, 0.f};
#pragma unroll
      for (int kc = 0; kc < 4; ++kc)
#pragma unroll
        for (int f = 0; f < 8; ++f) acc[f] = MFMA16(wfrag(f, kc), xf[kc], acc[f]);

      const int j = jb + l15;
#pragma unroll
      for (int f = 0; f < 8; ++f) {
        const int cc0 = 16 * f + 4 * g;
        s16x4 pv;
#pragma unroll
        for (int r = 0; r < 4; ++r) pv[r] = (short)f2bf(acc[f][r] + bias_v[f][r]);
        *(s16x4*)(out + (size_t)j * 128 + cc0) = pv;
      }
    }
  }
}

// ---------------------------------------------------------------------------
// Stage 2: per (head, 64-row Q-tile), 4 independent waves (16 Q-rows each).
// Swapped QK^T with permuted K-row feed: sigma(m) = 8*(m>>2) + (m&3), so that
// lane (g,l15) ends up holding P[q=l15][k = 8g..8g+7] per 32-col window ==
// exactly the PV A-fragment. Zero LDS, zero barriers, zero shuffles for the
// transpose. P stash = 16 x s16x8 (64 VGPR). K and V each read once.
// ---------------------------------------------------------------------------
__global__ __launch_bounds__(256, 3) void attn_kernel(
    const unsigned short* __restrict__ Qt, const unsigned short* __restrict__ Kt,
    const unsigned short* __restrict__ Vf, float* __restrict__ out0,
    float* __restrict__ attn_out) {
  const int tid = threadIdx.x;
  const int lane = tid & 63;
  const int wave = tid >> 6;
  const int l15 = lane & 15;
  const int g = lane >> 4;

  // XCD-aware bijective swizzle (4096 % 8 == 0)
  const int bid = blockIdx.x;
  const int nb = (bid & 7) * 512 + (bid >> 3);
  const int head = nb >> 3;
  const int h0 = (nb & 7) * 64;

  const float scale = 0.08838834764831845f;  // 1/sqrt(128)

  // Q as B-fragment: lane (g,l15) holds Q[row l15][c = 32kc + 8g..+7]
  const unsigned short* qbase =
      Qt + (size_t)head * 65536 + (size_t)(h0 + 16 * wave + l15) * 128 + 8 * g;
  s16x8 qf[4];
#pragma unroll
  for (int kc = 0; kc < 4; ++kc) qf[kc] = *(const s16x8*)(qbase + 32 * kc);

  // K as A-fragment with permuted row feed
  const int sig = 8 * (l15 >> 2) + (l15 & 3);
  const unsigned short* kbase = Kt + (size_t)head * 65536 + (size_t)sig * 128 + 8 * g;

  auto loadKc = [&](s16x8* kf, int c) {
    // chunk c: K rows 32*(c>>1) + 4*(c&1) + sigma(l15)
    const unsigned short* kp = kbase + (c >> 1) * 4096 + (c & 1) * 512;
#pragma unroll
    for (int kc = 0; kc < 4; ++kc) kf[kc] = *(const s16x8*)(kp + 32 * kc);
  };

  s16x8 stash[16];
  float rs = 0.f;

  // ---- phase A: S^T chunks -> exp -> pack into PV A-fragments ----
  s16x8 ka[4], kb[4];
  loadKc(ka, 0);
#pragma unroll
  for (int w = 0; w < 16; ++w) {
    loadKc(kb, 2 * w + 1);
    f32x4 sA = {0.f, 0.f, 0.f, 0.f};
#pragma unroll
    for (int kc = 0; kc < 4; ++kc) sA = MFMA16(ka[kc], qf[kc], sA);
    if (w < 15) loadKc(ka, 2 * w + 2);
    f32x4 sB = {0.f, 0.f, 0.f, 0.f};
#pragma unroll
    for (int kc = 0; kc < 4; ++kc) sB = MFMA16(kb[kc], qf[kc], sB);

    s16x8 fr;
#pragma unroll
    for (int r = 0; r < 4; ++r) {
      const float e = __expf(sA[r] * scale);
      rs += e;
      fr[r] = (short)f2bf(e);
    }
#pragma unroll
    for (int r = 0; r < 4; ++r) {
      const float e = __expf(sB[r] * scale);
      rs += e;
      fr[4 + r] = (short)f2bf(e);
    }
    stash[w] = fr;
  }

  // row l15's full sum: combine the 4 g-lane partials
  rs += __shfl_xor(rs, 16);
  rs += __shfl_xor(rs, 32);
  const float inv = 1.0f / rs;

  // ---- phase B: attn write (full-line) + PV accumulate ----
  f32x4 acc2[8];
#pragma unroll
  for (int f = 0; f < 8; ++f) acc2[f] = (f32x4){0.f, 0.f, 0.f, 0.f};

  const unsigned short* vbase = Vf + (size_t)head * 65536 + (size_t)l15 * 512 + 8 * g;
  float* ap = attn_out + (size_t)head * 262144 + (size_t)(h0 + 16 * wave + l15) * 512 + 8 * g;

#pragma unroll
  for (int w = 0; w < 16; ++w) {
    s16x8 vf[8];
#pragma unroll
    for (int f = 0; f < 8; ++f) vf[f] = *(const s16x8*)(vbase + w * 32 + (size_t)f * 8192);

    // attn write from the stash (independent of vf arrival)
    const s16x8 fr = stash[w];
    f32x4 o0, o1;
#pragma unroll
    for (int r = 0; r < 4; ++r) {
      o0[r] = bf2f((unsigned short)fr[r]) * inv;
      o1[r] = bf2f((unsigned short)fr[4 + r]) * inv;
    }
    *(f32x4*)(ap + w * 32) = o0;
    *(f32x4*)(ap + w * 32 + 4) = o1;

#pragma unroll
    for (int f = 0; f < 8; ++f) acc2[f] = MFMA16(fr, vf[f], acc2[f]);
  }

  // ---- out0: C rows m=4g+r need inv of row m (from lane m) ----
  float invm[4];
#pragma unroll
  for (int r = 0; r < 4; ++r) invm[r] = __shfl(inv, 4 * g + r);

  float* op = out0 + (size_t)head * 65536 + (size_t)(h0 + 16 * wave + 4 * g) * 128 + l15;
#pragma unroll
  for (int f = 0; f < 8; ++f)
#pragma unroll
    for (int r = 0; r < 4; ++r) op[(size_t)r * 128 + f * 16] = acc2[f][r] * invm[r];
}

extern "C" void kernel_launch(void* const* d_in, const int* in_sizes, int n_in,
                              void* d_out, int out_size, void* d_ws, size_t ws_size,
                              hipStream_t stream) {
  const float* q  = (const float*)d_in[0];
  const float* k  = (const float*)d_in[1];
  const float* v  = (const float*)d_in[2];
  const float* Wq = (const float*)d_in[3];
  const float* bq = (const float*)d_in[4];
  const float* Wk = (const float*)d_in[5];
  const float* bk = (const float*)d_in[6];
  const float* Wv = (const float*)d_in[7];
  const float* bv = (const float*)d_in[8];

  unsigned short* Qt = (unsigned short*)d_ws;       // 64 MiB
  unsigned short* Kt = Qt + 33554432;               // 64 MiB
  unsigned short* Vf = Kt + 33554432;               // 64 MiB
  float* out0 = (float*)d_out;                      // 33,554,432 fp32
  float* attn = out0 + 33554432;                    // 134,217,728 fp32

  dim3 pgrid(512, 3, 1);
  proj_kernel<<<pgrid, 256, 0, stream>>>(q, k, v, Wq, bq, Wk, bk, Wv, bv, Qt, Kt, Vf);
  attn_kernel<<<4096, 256, 0, stream>>>(Qt, Kt, Vf, out0, attn);
}

// Round 4
// 673.174 us; speedup vs baseline: 1.4350x; 1.2609x over previous
//
#include <hip/hip_runtime.h>
#include <stdint.h>

typedef float f32x4 __attribute__((ext_vector_type(4)));
typedef short s16x8 __attribute__((ext_vector_type(8)));
typedef short s16x4 __attribute__((ext_vector_type(4)));

#define MFMA16(a, b, c) __builtin_amdgcn_mfma_f32_16x16x32_bf16(a, b, c, 0, 0, 0)

__device__ __forceinline__ unsigned short f2bf(float f) {
  union { float f; uint32_t u; } v; v.f = f;
  return (unsigned short)((v.u + 0x7FFFu + ((v.u >> 16) & 1u)) >> 16);
}
__device__ __forceinline__ float bf2f(unsigned short s) {
  union { float f; uint32_t u; } v; v.u = ((uint32_t)s) << 16;
  return v.f;
}
__device__ __forceinline__ s16x8 cvt8(const float* p) {
  f32x4 a = *(const f32x4*)p;
  f32x4 b = *(const f32x4*)(p + 4);
  s16x8 t;
  t[0] = (short)f2bf(a[0]); t[1] = (short)f2bf(a[1]);
  t[2] = (short)f2bf(a[2]); t[3] = (short)f2bf(a[3]);
  t[4] = (short)f2bf(b[0]); t[5] = (short)f2bf(b[1]);
  t[6] = (short)f2bf(b[2]); t[7] = (short)f2bf(b[3]);
  return t;
}

template <int N> __device__ __forceinline__ void vmwait() {
  asm volatile("s_waitcnt vmcnt(%0)" ::"i"(N) : "memory");
}
__device__ __forceinline__ void blockbar() {
  __builtin_amdgcn_s_barrier();
  asm volatile("" ::: "memory");
}
__device__ __forceinline__ void gl_lds16(const void* g, void* l) {
  __builtin_amdgcn_global_load_lds((const __attribute__((address_space(1))) void*)g,
                                   (__attribute__((address_space(3))) void*)l, 16, 0, 0);
}

// ---------------------------------------------------------------------------
// Stage 1: Y = X @ W^T + b. Unchanged from R1/R2 (verified).
// ---------------------------------------------------------------------------
__global__ __launch_bounds__(256) void proj_kernel(
    const float* __restrict__ Xq, const float* __restrict__ Xk, const float* __restrict__ Xv,
    const float* __restrict__ Wq, const float* __restrict__ bq,
    const float* __restrict__ Wk, const float* __restrict__ bk,
    const float* __restrict__ Wv, const float* __restrict__ bv,
    unsigned short* __restrict__ Qt, unsigned short* __restrict__ Kt,
    unsigned short* __restrict__ Vf) {
  __shared__ unsigned char Wsh[32768];

  const int ty = blockIdx.y;
  const float* X = (ty == 0) ? Xq : (ty == 1) ? Xk : Xv;
  const float* W = (ty == 0) ? Wq : (ty == 1) ? Wk : Wv;
  const float* B = (ty == 0) ? bq : (ty == 1) ? bk : bv;
  unsigned short* out = (ty == 0) ? Qt : (ty == 1) ? Kt : Vf;
  const bool transposed = (ty != 2);

  const int tid = threadIdx.x;
  const int lane = tid & 63;
  const int wave = tid >> 6;
  const int l15 = lane & 15;
  const int g = lane >> 4;

  {
    const int r = tid >> 1;
    const int cb = (tid & 1) * 64;
    const float* wp = W + (size_t)r * 128 + cb;
#pragma unroll
    for (int c8 = 0; c8 < 8; ++c8) {
      s16x8 w = cvt8(wp + 8 * c8);
      const int byte = r * 256 + ((cb * 2 + c8 * 16) ^ ((r & 7) << 4));
      *(s16x8*)(Wsh + byte) = w;
    }
  }
  __syncthreads();

  auto wfrag = [&](int f, int kc) -> s16x8 {
    const int row = 16 * f + l15;
    return *(const s16x8*)(Wsh + row * 256 + ((64 * kc + 16 * g) ^ ((row & 7) << 4)));
  };

  if (transposed) {
    float bias_s[8];
#pragma unroll
    for (int f = 0; f < 8; ++f) bias_s[f] = B[16 * f + l15];

    for (int t = 0; t < 8; ++t) {
      const int jb = blockIdx.x * 512 + t * 64 + wave * 16;
      const int jrow = jb + (l15 >> 2) + 4 * (l15 & 3);
      const float* xr = X + (size_t)jrow * 128 + 8 * g;
      s16x8 xf[4];
#pragma unroll
      for (int kc = 0; kc < 4; ++kc) xf[kc] = cvt8(xr + 32 * kc);

      f32x4 acc[8];
#pragma unroll
      for (int f = 0; f < 8; ++f) acc[f] = (f32x4){0.f, 0.f, 0.f, 0.f};
#pragma unroll
      for (int kc = 0; kc < 4; ++kc)
#pragma unroll
        for (int f = 0; f < 8; ++f) acc[f] = MFMA16(xf[kc], wfrag(f, kc), acc[f]);

      const int n = jb >> 9;
      const int c0 = (jb & 511) >> 2;
#pragma unroll
      for (int f = 0; f < 8; ++f) {
        const int h = 128 * g + 16 * f + l15;
        s16x4 pv;
#pragma unroll
        for (int r = 0; r < 4; ++r) pv[r] = (short)f2bf(acc[f][r] + bias_s[f]);
        *(s16x4*)(out + (size_t)n * 65536 + (size_t)h * 128 + c0) = pv;
      }
    }
  } else {
    f32x4 bias_v[8];
#pragma unroll
    for (int f = 0; f < 8; ++f) bias_v[f] = *(const f32x4*)(B + 16 * f + 4 * g);

    for (int t = 0; t < 8; ++t) {
      const int jb = blockIdx.x * 512 + t * 64 + wave * 16;
      const int jrow = jb + l15;
      const float* xr = X + (size_t)jrow * 128 + 8 * g;
      s16x8 xf[4];
#pragma unroll
      for (int kc = 0; kc < 4; ++kc) xf[kc] = cvt8(xr + 32 * kc);

      f32x4 acc[8];
#pragma unroll
      for (int f = 0; f < 8; ++f) acc[f] = (f32x4){0.f, 0.f, 0.f, 0.f};
#pragma unroll
      for (int kc = 0; kc < 4; ++kc)
#pragma unroll
        for (int f = 0; f < 8; ++f) acc[f] = MFMA16(wfrag(f, kc), xf[kc], acc[f]);

      const int j = jb + l15;
#pragma unroll
      for (int f = 0; f < 8; ++f) {
        const int cc0 = 16 * f + 4 * g;
        s16x4 pv;
#pragma unroll
        for (int r = 0; r < 4; ++r) pv[r] = (short)f2bf(acc[f][r] + bias_v[f][r]);
        *(s16x4*)(out + (size_t)j * 128 + cc0) = pv;
      }
    }
  }
}

// ---------------------------------------------------------------------------
// Stage 2a (qk): S^T = K·Q^T (swapped, permuted row feed sigma), exp, rowsum.
// Unnormalized P (bf16) stored in the SECOND HALF of each attn row
// (bytes 1024..2047 of the 2048B f32 row); 1/rowsum stored at out0[row][0].
// K staged per 32-col window into fragment-major LDS (8 x 1KB, lane*16 order)
// via global_load_lds, shared by all 4 waves; 3 buffers, counted vmcnt.
// ---------------------------------------------------------------------------
__global__ __launch_bounds__(256, 4) void qk_kernel(
    const unsigned short* __restrict__ Qt, const unsigned short* __restrict__ Kt,
    unsigned short* __restrict__ Pout, float* __restrict__ out0) {
  __shared__ unsigned char Ksh[24576];

  const int tid = threadIdx.x;
  const int lane = tid & 63;
  const int wave = tid >> 6;
  const int l15 = lane & 15;
  const int g = lane >> 4;

  const int bid = blockIdx.x;
  const int nb = (bid & 7) * 512 + (bid >> 3);
  const int head = nb >> 3;
  const int h0 = (nb & 7) * 64;
  const float scale = 0.08838834764831845f;

  const size_t khead = (size_t)head * 65536;
  const unsigned short* qbase =
      Qt + khead + (size_t)(h0 + 16 * wave + l15) * 128 + 8 * g;
  s16x8 qf[4];
#pragma unroll
  for (int kc = 0; kc < 4; ++kc) qf[kc] = *(const s16x8*)(qbase + 32 * kc);

  const int sig = 8 * (l15 >> 2) + (l15 & 3);
  const int phi0 = 2 * wave;

  auto stageK = [&](int w) {
    const int buf = w % 3;
#pragma unroll
    for (int j = 0; j < 2; ++j) {
      const int phi = phi0 + j;
      const int cp = phi >> 2, kc = phi & 3;
      const unsigned short* src =
          Kt + khead + (size_t)(32 * w + 4 * cp + sig) * 128 + 32 * kc + 8 * g;
      gl_lds16(src, Ksh + buf * 8192 + phi * 1024);
    }
  };

  stageK(0);
  stageK(1);

  float rs = 0.f;
  unsigned short* pbase =
      Pout + (size_t)head * 524288 + (size_t)(h0 + 16 * wave + l15) * 1024 + 512 + 8 * g;

#pragma unroll
  for (int w = 0; w < 16; ++w) {
    if (w == 0) vmwait<0>();
    else if (w == 15) vmwait<1>();
    else vmwait<3>();
    blockbar();

    const unsigned char* kb8 = Ksh + (w % 3) * 8192;
    const int lb = lane * 16;
    s16x8 ka0 = *(const s16x8*)(kb8 + lb);
    s16x8 ka1 = *(const s16x8*)(kb8 + 1024 + lb);
    s16x8 ka2 = *(const s16x8*)(kb8 + 2048 + lb);
    s16x8 ka3 = *(const s16x8*)(kb8 + 3072 + lb);
    s16x8 kb0 = *(const s16x8*)(kb8 + 4096 + lb);
    s16x8 kb1 = *(const s16x8*)(kb8 + 5120 + lb);
    s16x8 kb2 = *(const s16x8*)(kb8 + 6144 + lb);
    s16x8 kb3 = *(const s16x8*)(kb8 + 7168 + lb);

    f32x4 sA = {0.f, 0.f, 0.f, 0.f}, sB = {0.f, 0.f, 0.f, 0.f};
    sA = MFMA16(ka0, qf[0], sA); sA = MFMA16(ka1, qf[1], sA);
    sA = MFMA16(ka2, qf[2], sA); sA = MFMA16(ka3, qf[3], sA);
    sB = MFMA16(kb0, qf[0], sB); sB = MFMA16(kb1, qf[1], sB);
    sB = MFMA16(kb2, qf[2], sB); sB = MFMA16(kb3, qf[3], sB);

    s16x8 fr;
#pragma unroll
    for (int r = 0; r < 4; ++r) {
      const float e = __expf(sA[r] * scale);
      rs += e;
      fr[r] = (short)f2bf(e);
    }
#pragma unroll
    for (int r = 0; r < 4; ++r) {
      const float e = __expf(sB[r] * scale);
      rs += e;
      fr[4 + r] = (short)f2bf(e);
    }

    if (w < 14) stageK(w + 2);
    *(s16x8*)(pbase + w * 32) = fr;
  }

  rs += __shfl_xor(rs, 16);
  rs += __shfl_xor(rs, 32);
  if (g == 0)
    out0[(size_t)head * 65536 + (size_t)(h0 + 16 * wave + l15) * 128] = 1.0f / rs;
}

// ---------------------------------------------------------------------------
// Stage 2b (pv): read P bf16 (in attn rows' second half) + inv, write
// normalized attn f32 (full lines; window w>=8 overwrites already-consumed P),
// PV-accumulate with V staged fragment-major in LDS, write out0.
// ---------------------------------------------------------------------------
__global__ __launch_bounds__(256, 4) void pv_kernel(
    const unsigned short* __restrict__ Vf, float* attn, float* out0) {
  __shared__ unsigned char Vsh[24576];

  const int tid = threadIdx.x;
  const int lane = tid & 63;
  const int wave = tid >> 6;
  const int l15 = lane & 15;
  const int g = lane >> 4;

  const int bid = blockIdx.x;
  const int nb = (bid & 7) * 512 + (bid >> 3);
  const int head = nb >> 3;
  const int h0 = (nb & 7) * 64;

  const int row = h0 + 16 * wave + l15;
  const float invq = out0[(size_t)head * 65536 + (size_t)row * 128];

  const unsigned short* pb16 = (const unsigned short*)attn;
  const unsigned short* pbase =
      pb16 + (size_t)head * 524288 + (size_t)row * 1024 + 512 + 8 * g;
  float* ap = attn + (size_t)head * 262144 + (size_t)row * 512 + 8 * g;

  const size_t vhead = (size_t)head * 65536;
  const int phi0 = 2 * wave;

  auto stageV = [&](int w) {
    const int buf = w % 3;
#pragma unroll
    for (int j = 0; j < 2; ++j) {
      const int f = phi0 + j;
      const unsigned short* src =
          Vf + vhead + (size_t)(l15 + 16 * f) * 512 + w * 32 + 8 * g;
      gl_lds16(src, Vsh + buf * 8192 + f * 1024);
    }
  };

  stageV(0);
  stageV(1);
  s16x8 pf0 = *(const s16x8*)(pbase);
  s16x8 pf1;

  f32x4 acc2[8];
#pragma unroll
  for (int f = 0; f < 8; ++f) acc2[f] = (f32x4){0.f, 0.f, 0.f, 0.f};

#pragma unroll
  for (int w = 0; w < 16; ++w) {
    if (w == 0) vmwait<0>();
    else if (w == 15) vmwait<3>();
    else vmwait<5>();
    blockbar();

    if (w < 15) {
      if ((w & 1) == 0) pf1 = *(const s16x8*)(pbase + (w + 1) * 32);
      else pf0 = *(const s16x8*)(pbase + (w + 1) * 32);
    }
    const s16x8 pc = ((w & 1) == 0) ? pf0 : pf1;

    f32x4 o0, o1;
#pragma unroll
    for (int r = 0; r < 4; ++r) {
      o0[r] = bf2f((unsigned short)pc[r]) * invq;
      o1[r] = bf2f((unsigned short)pc[4 + r]) * invq;
    }
    *(f32x4*)(ap + w * 32) = o0;
    *(f32x4*)(ap + w * 32 + 4) = o1;

    const unsigned char* vb8 = Vsh + (w % 3) * 8192;
    const int lb = lane * 16;
#pragma unroll
    for (int f = 0; f < 8; ++f) {
      s16x8 vf = *(const s16x8*)(vb8 + f * 1024 + lb);
      acc2[f] = MFMA16(pc, vf, acc2[f]);
    }

    if (w < 14) stageV(w + 2);
  }

  float invm[4];
#pragma unroll
  for (int r = 0; r < 4; ++r) invm[r] = __shfl(invq, 4 * g + r);

  float* op = out0 + (size_t)head * 65536 + (size_t)(h0 + 16 * wave + 4 * g) * 128 + l15;
#pragma unroll
  for (int f = 0; f < 8; ++f)
#pragma unroll
    for (int r = 0; r < 4; ++r) op[(size_t)r * 128 + f * 16] = acc2[f][r] * invm[r];
}

extern "C" void kernel_launch(void* const* d_in, const int* in_sizes, int n_in,
                              void* d_out, int out_size, void* d_ws, size_t ws_size,
                              hipStream_t stream) {
  const float* q  = (const float*)d_in[0];
  const float* k  = (const float*)d_in[1];
  const float* v  = (const float*)d_in[2];
  const float* Wq = (const float*)d_in[3];
  const float* bq = (const float*)d_in[4];
  const float* Wk = (const float*)d_in[5];
  const float* bk = (const float*)d_in[6];
  const float* Wv = (const float*)d_in[7];
  const float* bv = (const float*)d_in[8];

  unsigned short* Qt = (unsigned short*)d_ws;       // 64 MiB
  unsigned short* Kt = Qt + 33554432;               // 64 MiB
  unsigned short* Vf = Kt + 33554432;               // 64 MiB
  float* out0 = (float*)d_out;                      // 33,554,432 fp32
  float* attn = out0 + 33554432;                    // 134,217,728 fp32

  dim3 pgrid(512, 3, 1);
  proj_kernel<<<pgrid, 256, 0, stream>>>(q, k, v, Wq, bq, Wk, bk, Wv, bv, Qt, Kt, Vf);
  qk_kernel<<<4096, 256, 0, stream>>>(Qt, Kt, (unsigned short*)attn, out0);
  pv_kernel<<<4096, 256, 0, stream>>>(Vf, attn, out0);
}